// Round 7
// baseline (233.895 us; speedup 1.0000x reference)
//
#include <hip/hip_runtime.h>

typedef _Float16 f16x2 __attribute__((ext_vector_type(2)));
typedef _Float16 f16x8 __attribute__((ext_vector_type(8)));
typedef __fp16   fp16v2 __attribute__((ext_vector_type(2)));   // cvt_pkrtz return type
typedef float    f32x4 __attribute__((ext_vector_type(4)));
typedef unsigned int u32x4 __attribute__((ext_vector_type(4)));

#define TSTRIDE 17   // T row stride in 32-bit words (odd -> 2 lanes/bank epilogue reads = free)

__device__ __forceinline__ f16x2 pk2(float lo, float hi) {
    fp16v2 p = __builtin_amdgcn_cvt_pkrtz(lo, hi);
    return __builtin_bit_cast(f16x2, p);
}

// ---- prep: C (f32) -> frag-ordered f16 B in workspace (once per launch) ----
// chunk = (2s+t)*48 + (16gg+cc): v[e] = f16(C[16t+cc][s][8gg+e]); i>=24 -> 0
__global__ __launch_bounds__(256) void prep_B(const float* __restrict__ coeffs,
                                              f16x8* __restrict__ wsB)
{
    int chunk = blockIdx.x * 256 + threadIdx.x;   // 0..2303 (grid 9 x 256 exact)
    int f  = chunk / 48, sl = chunk % 48;
    int s  = f >> 1,  tt = f & 1;
    int gg = sl >> 4, cc = sl & 15;
    int i  = 16 * tt + cc;
    f16x8 v;
    if (i < 24) {
        const float* src = coeffs + i * 576 + s * 24 + gg * 8;
#pragma unroll
        for (int e = 0; e < 8; ++e) v[e] = (_Float16)src[e];
    } else {
#pragma unroll
        for (int e = 0; e < 8; ++e) v[e] = (_Float16)0.f;
    }
    wsB[chunk] = v;
}

// ---- main: out[n] = sum_i sx_i * T[n,i], T[n,i] = sum_{j,k} sy_j sz_k C[i,j,k]
// fp16 MFMA 16x16x32: M=points (4 tiles of 16 / wave), N=i (2 tiles), K-step s == j.
// Native v_sin/v_cos take REVOLUTIONS: sin(2pi*x) = __builtin_amdgcn_sinf(x).
// launch_bounds(512,8): <=64 VGPR -> 8 waves/SIMD -> 4 blocks/CU (LDS 4x36864 fits).
__global__ __launch_bounds__(512, 8) void fourier_main(
    const float* __restrict__ xyz,
    const f16x8* __restrict__ wsB,
    float* __restrict__ out)
{
    __shared__ __align__(16) f16x8 Bl[2304];   // 36864 B; T overlay 8*64*17*4=34816 B

    const int tid  = threadIdx.x;
    const int wave = tid >> 6;
    const int lane = tid & 63;
    const int g    = lane >> 4;   // k-group
    const int c    = lane & 15;   // A-row / B-col within fragment

    // stage B from ws (coalesced 16B copies)
#pragma unroll
    for (int pass = 0; pass < 4; ++pass)
        Bl[pass * 512 + tid] = wsB[pass * 512 + tid];
    if (tid < 256) Bl[2048 + tid] = wsB[2048 + tid];

    const int p0 = (blockIdx.x * 8 + wave) * 64;   // 64 points per wave

    // preload epilogue x NOW (hide HBM latency behind setup + main loop)
    const float xv = xyz[3 * (p0 + lane)];

    float syp[4], syc[4], c2y[4];   // fp32 sin(j*thy) recurrence per M-tile
    f16x2 sz2[4][4];                // packed f16 sin((8g+e)*thz)
    const float kmask = (g < 3) ? 1.0f : 0.0f;   // k>=24 pad -> zero A

#pragma unroll
    for (int m = 0; m < 4; ++m) {
        int p = p0 + 16 * m + c;
        float y = xyz[3 * p + 1];
        float z = xyz[3 * p + 2];
        float sy1 = __builtin_amdgcn_sinf(y);
        float cy1 = __builtin_amdgcn_cosf(y);
        syp[m] = 0.f; syc[m] = sy1; c2y[m] = 2.f * cy1;
        float sz1 = __builtin_amdgcn_sinf(z);
        float cz1 = __builtin_amdgcn_cosf(z);
        float wv  = __builtin_amdgcn_fractf((float)(8 * g) * z);
        float sb  = __builtin_amdgcn_sinf(wv) * kmask;   // sin(8g*thz), masked
        float cb  = __builtin_amdgcn_cosf(wv);
        float c2z = 2.f * cz1;
        float szf[8];
        szf[0] = sb;
        szf[1] = fmaf(sb, cz1, cb * sz1 * kmask);
#pragma unroll
        for (int e = 2; e < 8; ++e) szf[e] = fmaf(c2z, szf[e - 1], -szf[e - 2]);
#pragma unroll
        for (int q = 0; q < 4; ++q) sz2[m][q] = pk2(szf[2 * q], szf[2 * q + 1]);
    }

    f32x4 acc[4][2] = {};

    __syncthreads();

    const int bslot = (lane < 48) ? lane : 47;  // g==3: A=0, B value irrelevant
    // main loop: s = j (j=0 contributes 0, skipped); ds offsets fold to immediates
#pragma unroll
    for (int s = 1; s < 24; ++s) {
        f16x8 b0 = Bl[(2 * s + 0) * 48 + bslot];
        f16x8 b1 = Bl[(2 * s + 1) * 48 + bslot];
#pragma unroll
        for (int m = 0; m < 4; ++m) {
            f16x2 hy2 = pk2(syc[m], syc[m]);       // 1 instr: cvt + broadcast
            u32x4 aw;
#pragma unroll
            for (int q = 0; q < 4; ++q) {          // 4x v_pk_mul_f16
                f16x2 pr = hy2 * sz2[m][q];
                aw[q] = __builtin_bit_cast(unsigned int, pr);
            }
            f16x8 a = __builtin_bit_cast(f16x8, aw);
            acc[m][0] = __builtin_amdgcn_mfma_f32_16x16x32_f16(a, b0, acc[m][0], 0, 0, 0);
            acc[m][1] = __builtin_amdgcn_mfma_f32_16x16x32_f16(a, b1, acc[m][1], 0, 0, 0);
            float nxt = fmaf(c2y[m], syc[m], -syp[m]);
            syp[m] = syc[m]; syc[m] = nxt;
        }
    }

    __syncthreads();   // all waves done reading B -> safe to overlay T

    // scatter T: word (lr*TSTRIDE + c) = pk(acc[t=0][r], acc[t=1][r])
    // word w of a row holds i=w (lo) and i=16+w (hi; i>=24 slots are zero)
    unsigned int* Tw = (unsigned int*)Bl + wave * (64 * TSTRIDE);
#pragma unroll
    for (int m = 0; m < 4; ++m)
#pragma unroll
        for (int r = 0; r < 4; ++r) {
            int lr = 16 * m + 4 * g + r;          // D row = (lane>>4)*4 + reg
            fp16v2 pk = __builtin_amdgcn_cvt_pkrtz(acc[m][0][r], acc[m][1][r]);
            Tw[lr * TSTRIDE + c] = __builtin_bit_cast(unsigned int, pk);
        }

    // T region is wave-private (written and read only by this wave):
    // no block barrier needed, just drain our own LDS writes.
    asm volatile("s_waitcnt lgkmcnt(0)" ::: "memory");

    // epilogue: lane owns row lane (64 rows/wave), fully coalesced store
    {
        int p = p0 + lane;
        float s1  = __builtin_amdgcn_sinf(xv);
        float c1  = __builtin_amdgcn_cosf(xv);
        float w16 = __builtin_amdgcn_fractf(16.f * xv);   // 16x exact in f32
        float s16 = __builtin_amdgcn_sinf(w16);
        float c16 = __builtin_amdgcn_cosf(w16);
        const float c2x = 2.f * c1;
        float sA0 = 0.f,  sA1 = s1;                        // sin(2pi*w*x)
        float sB0 = s16,  sB1 = fmaf(s16, c1, c16 * s1);   // sin(2pi*(16+w)*x)
        float res = 0.f;
        const unsigned int* Tr = Tw + lane * TSTRIDE;
#pragma unroll
        for (int w = 0; w < 16; ++w) {
            f16x2 h = __builtin_bit_cast(f16x2, Tr[w]);
            res = fmaf(sA0, (float)h[0], res);
            res = fmaf(sB0, (float)h[1], res);   // i>=24: T==0
            float nA = fmaf(c2x, sA1, -sA0);
            float nB = fmaf(c2x, sB1, -sB0);
            sA0 = sA1; sA1 = nA;
            sB0 = sB1; sB1 = nB;
        }
        out[p] = res;
    }
}

extern "C" void kernel_launch(void* const* d_in, const int* in_sizes, int n_in,
                              void* d_out, int out_size, void* d_ws, size_t ws_size,
                              hipStream_t stream) {
    const float* xyz    = (const float*)d_in[0];
    const float* coeffs = (const float*)d_in[1];
    float* out = (float*)d_out;
    f16x8* wsB = (f16x8*)d_ws;                 // needs 36864 B

    prep_B<<<9, 256, 0, stream>>>(coeffs, wsB);

    const int n = in_sizes[0] / 3;             // 524288 = 1024 blocks * 8 waves * 64
    const int grid = n / 512;
    fourier_main<<<grid, 512, 0, stream>>>(xyz, wsB, out);
}

// Round 8
// 33.801 us; speedup vs baseline: 6.9198x; 6.9198x over previous
//
#include <hip/hip_runtime.h>

typedef _Float16 f16x2 __attribute__((ext_vector_type(2)));
typedef _Float16 f16x8 __attribute__((ext_vector_type(8)));
typedef __fp16   fp16v2 __attribute__((ext_vector_type(2)));   // cvt_pkrtz return type
typedef float    f32x4 __attribute__((ext_vector_type(4)));
typedef unsigned int u32x4 __attribute__((ext_vector_type(4)));

#define TSTRIDE 17   // T row stride in words: odd -> epilogue reads 2 lanes/bank (free)

__device__ __forceinline__ f16x2 pk2(float lo, float hi) {
    fp16v2 p = __builtin_amdgcn_cvt_pkrtz(lo, hi);
    return __builtin_bit_cast(f16x2, p);
}

// ---- prep: C (f32) -> frag-ordered f16 B in workspace (once per launch) ----
// chunk = (2s+t)*48 + (16gg+cc): v[e] = f16(C[16t+cc][s][8gg+e]); i>=24 -> 0
__global__ __launch_bounds__(256) void prep_B(const float* __restrict__ coeffs,
                                              f16x8* __restrict__ wsB)
{
    int chunk = blockIdx.x * 256 + threadIdx.x;   // 0..2303 (grid 9 x 256 exact)
    int f  = chunk / 48, sl = chunk % 48;
    int s  = f >> 1,  tt = f & 1;
    int gg = sl >> 4, cc = sl & 15;
    int i  = 16 * tt + cc;
    f16x8 v;
    if (i < 24) {
        const float* src = coeffs + i * 576 + s * 24 + gg * 8;
#pragma unroll
        for (int e = 0; e < 8; ++e) v[e] = (_Float16)src[e];
    } else {
#pragma unroll
        for (int e = 0; e < 8; ++e) v[e] = (_Float16)0.f;
    }
    wsB[chunk] = v;
}

// ---- main: out[n] = sum_i sx_i * T[n,i], T[n,i] = sum_{j,k} sy_j sz_k C[i,j,k]
// fp16 MFMA 16x16x32: Mt=8 point-tiles of 16 per wave (128 pts), N=i (2 tiles),
// K-step s == j, k padded to 32 (pad zeroed on A side).
// Native v_sin/v_cos take REVOLUTIONS: sin(2pi*x) = __builtin_amdgcn_sinf(x).
// NO min-waves bound: R7 showed forcing occupancy -> 32 VGPR -> scratch spill disaster.
__global__ __launch_bounds__(256) void fourier_main(
    const float* __restrict__ xyz,
    const f16x8* __restrict__ wsB,
    float* __restrict__ out)
{
    __shared__ __align__(16) f16x8 Bl[2304];   // 36864 B; T overlay 4*128*17*4=34816 B

    const int tid  = threadIdx.x;
    const int wave = tid >> 6;
    const int lane = tid & 63;
    const int g    = lane >> 4;   // k-group
    const int c    = lane & 15;   // A-row / B-col within fragment

    // stage B from ws: 2304 chunks / 256 threads = 9 coalesced 16B copies
#pragma unroll
    for (int pass = 0; pass < 9; ++pass)
        Bl[pass * 256 + tid] = wsB[pass * 256 + tid];

    const int p0 = (blockIdx.x * 4 + wave) * 128;   // 128 points per wave

    // preload epilogue x now (HBM latency hides behind setup + main loop)
    const float xv0 = xyz[3 * (p0 + lane)];
    const float xv1 = xyz[3 * (p0 + 64 + lane)];

    float syp[8], syc[8], c2y[8];   // fp32 sin(j*thy) recurrence per M-tile
    f16x2 sz2[8][4];                // packed f16 sin((8g+e)*thz)
    const float kmask = (g < 3) ? 1.0f : 0.0f;   // k>=24 pad -> zero A

#pragma unroll
    for (int m = 0; m < 8; ++m) {
        int p = p0 + 16 * m + c;
        float y = xyz[3 * p + 1];
        float z = xyz[3 * p + 2];
        float sy1 = __builtin_amdgcn_sinf(y);
        float cy1 = __builtin_amdgcn_cosf(y);
        syp[m] = 0.f; syc[m] = sy1; c2y[m] = 2.f * cy1;
        float sz1 = __builtin_amdgcn_sinf(z);
        float cz1 = __builtin_amdgcn_cosf(z);
        float wv  = __builtin_amdgcn_fractf((float)(8 * g) * z);
        float sb  = __builtin_amdgcn_sinf(wv) * kmask;   // sin(8g*thz), masked
        float cb  = __builtin_amdgcn_cosf(wv);
        float c2z = 2.f * cz1;
        float szf[8];
        szf[0] = sb;
        szf[1] = fmaf(sb, cz1, cb * sz1 * kmask);
#pragma unroll
        for (int e = 2; e < 8; ++e) szf[e] = fmaf(c2z, szf[e - 1], -szf[e - 2]);
#pragma unroll
        for (int q = 0; q < 4; ++q) sz2[m][q] = pk2(szf[2 * q], szf[2 * q + 1]);
    }

    f32x4 acc[8][2] = {};

    __syncthreads();

    const int bslot = (lane < 48) ? lane : 47;  // g==3: A=0, B value irrelevant

    // main loop: s = j (j=0 contributes 0, skipped); rolled with next-s prefetch
    f16x8 nb0 = Bl[96 + bslot];    // (2*1+0)*48
    f16x8 nb1 = Bl[144 + bslot];   // (2*1+1)*48
#pragma unroll 1
    for (int s = 1; s < 24; ++s) {
        f16x8 b0 = nb0, b1 = nb1;
        int sn = (s < 23) ? s + 1 : 23;    // harmless redundant reload at s=23
        nb0 = Bl[(2 * sn + 0) * 48 + bslot];
        nb1 = Bl[(2 * sn + 1) * 48 + bslot];
#pragma unroll
        for (int m = 0; m < 8; ++m) {
            f16x2 hy2 = pk2(syc[m], syc[m]);       // 1 instr: cvt + broadcast
            u32x4 aw;
#pragma unroll
            for (int q = 0; q < 4; ++q) {          // 4x v_pk_mul_f16
                f16x2 pr = hy2 * sz2[m][q];
                aw[q] = __builtin_bit_cast(unsigned int, pr);
            }
            f16x8 a = __builtin_bit_cast(f16x8, aw);
            acc[m][0] = __builtin_amdgcn_mfma_f32_16x16x32_f16(a, b0, acc[m][0], 0, 0, 0);
            acc[m][1] = __builtin_amdgcn_mfma_f32_16x16x32_f16(a, b1, acc[m][1], 0, 0, 0);
            float nxt = fmaf(c2y[m], syc[m], -syp[m]);
            syp[m] = syc[m]; syc[m] = nxt;
        }
    }

    __syncthreads();   // all waves done reading B (cross-wave hazard) -> overlay T

    // scatter T: word (lr*TSTRIDE + c) = pk(acc[t=0][r], acc[t=1][r])
    // word w of a row holds i=w (lo) and i=16+w (hi; i>=24 slots are zero)
    unsigned int* Tw = (unsigned int*)Bl + wave * (128 * TSTRIDE);
#pragma unroll
    for (int m = 0; m < 8; ++m)
#pragma unroll
        for (int r = 0; r < 4; ++r) {
            int lr = 16 * m + 4 * g + r;          // D row = (lane>>4)*4 + reg
            fp16v2 pk = __builtin_amdgcn_cvt_pkrtz(acc[m][0][r], acc[m][1][r]);
            Tw[lr * TSTRIDE + c] = __builtin_bit_cast(unsigned int, pk);
        }

    // T region is wave-private: drain our own LDS writes, no block barrier.
    asm volatile("s_waitcnt lgkmcnt(0)" ::: "memory");

    // epilogue: 2 rows per lane (lane, lane+64), coalesced stores
#pragma unroll
    for (int h = 0; h < 2; ++h) {
        int row = 64 * h + lane;
        int p   = p0 + row;
        float xv = (h == 0) ? xv0 : xv1;
        float s1  = __builtin_amdgcn_sinf(xv);
        float c1  = __builtin_amdgcn_cosf(xv);
        float w16 = __builtin_amdgcn_fractf(16.f * xv);   // 16x exact in f32
        float s16 = __builtin_amdgcn_sinf(w16);
        float c16 = __builtin_amdgcn_cosf(w16);
        const float c2x = 2.f * c1;
        float sA0 = 0.f,  sA1 = s1;                        // sin(2pi*w*x)
        float sB0 = s16,  sB1 = fmaf(s16, c1, c16 * s1);   // sin(2pi*(16+w)*x)
        float res = 0.f;
        const unsigned int* Tr = Tw + row * TSTRIDE;
#pragma unroll
        for (int w = 0; w < 16; ++w) {
            f16x2 hh = __builtin_bit_cast(f16x2, Tr[w]);
            res = fmaf(sA0, (float)hh[0], res);
            res = fmaf(sB0, (float)hh[1], res);   // i>=24: T==0
            float nA = fmaf(c2x, sA1, -sA0);
            float nB = fmaf(c2x, sB1, -sB0);
            sA0 = sA1; sA1 = nA;
            sB0 = sB1; sB1 = nB;
        }
        out[p] = res;
    }
}

extern "C" void kernel_launch(void* const* d_in, const int* in_sizes, int n_in,
                              void* d_out, int out_size, void* d_ws, size_t ws_size,
                              hipStream_t stream) {
    const float* xyz    = (const float*)d_in[0];
    const float* coeffs = (const float*)d_in[1];
    float* out = (float*)d_out;
    f16x8* wsB = (f16x8*)d_ws;                 // needs 36864 B

    prep_B<<<9, 256, 0, stream>>>(coeffs, wsB);

    const int n = in_sizes[0] / 3;             // 524288 = 1024 blocks * 4 waves * 128
    const int grid = n / 512;
    fourier_main<<<grid, 256, 0, stream>>>(xyz, wsB, out);
}

// Round 9
// 31.965 us; speedup vs baseline: 7.3173x; 1.0574x over previous
//
#include <hip/hip_runtime.h>

typedef _Float16 f16x2 __attribute__((ext_vector_type(2)));
typedef _Float16 f16x8 __attribute__((ext_vector_type(8)));
typedef __fp16   fp16v2 __attribute__((ext_vector_type(2)));   // cvt_pkrtz return type
typedef float    f32x4 __attribute__((ext_vector_type(4)));
typedef unsigned int u32x4 __attribute__((ext_vector_type(4)));

#define TSTRIDE 17   // T row stride in words: odd -> epilogue reads 2 lanes/bank (free)

__device__ __forceinline__ f16x2 pk2(float lo, float hi) {
    fp16v2 p = __builtin_amdgcn_cvt_pkrtz(lo, hi);
    return __builtin_bit_cast(f16x2, p);
}

// ---- prep: C (f32) -> frag-ordered f16 B in workspace (once per launch) ----
// chunk = (2s+t)*48 + (16gg+cc): v[e] = f16(C[16t+cc][s][8gg+e]); i>=24 -> 0
__global__ __launch_bounds__(256) void prep_B(const float* __restrict__ coeffs,
                                              f16x8* __restrict__ wsB)
{
    int chunk = blockIdx.x * 256 + threadIdx.x;   // 0..2303 (grid 9 x 256 exact)
    int f  = chunk / 48, sl = chunk % 48;
    int s  = f >> 1,  tt = f & 1;
    int gg = sl >> 4, cc = sl & 15;
    int i  = 16 * tt + cc;
    f16x8 v;
    if (i < 24) {
        const float* src = coeffs + i * 576 + s * 24 + gg * 8;
#pragma unroll
        for (int e = 0; e < 8; ++e) v[e] = (_Float16)src[e];
    } else {
#pragma unroll
        for (int e = 0; e < 8; ++e) v[e] = (_Float16)0.f;
    }
    wsB[chunk] = v;
}

// ---- main: out[n] = sum_i sx_i * T[n,i], T[n,i] = sum_{j,k} sy_j sz_k C[i,j,k]
// fp16 MFMA 16x16x32: Mt=4 tiles of 16 pts per wave, N=i (2 tiles), K-step s == j.
// B is read STRAIGHT FROM GLOBAL (36 KB, L1-resident, one coalesced 768B row per
// wave-instruction) -> LDS pipe carries only the T scatter/epilogue; no staging,
// no block barriers (T region is wave-private).
// Native v_sin/v_cos take REVOLUTIONS: sin(2pi*x) = __builtin_amdgcn_sinf(x).
__global__ __launch_bounds__(512, 4) void fourier_main(
    const float* __restrict__ xyz,
    const f16x8* __restrict__ wsB,
    float* __restrict__ out)
{
    __shared__ __align__(16) unsigned int Tl[8 * 64 * TSTRIDE];   // 34816 B

    const int tid  = threadIdx.x;
    const int wave = tid >> 6;
    const int lane = tid & 63;
    const int g    = lane >> 4;   // k-group
    const int c    = lane & 15;   // A-row / B-col within fragment

    const int p0 = (blockIdx.x * 8 + wave) * 64;   // 64 points per wave

    // preload epilogue x now (HBM latency hides behind setup + main loop)
    const float xv = xyz[3 * (p0 + lane)];

    float syp[4], syc[4], c2y[4];   // fp32 sin(j*thy) recurrence per M-tile
    f16x2 sz2[4][4];                // packed f16 sin((8g+e)*thz)
    const float kmask = (g < 3) ? 1.0f : 0.0f;   // k>=24 pad -> zero A

#pragma unroll
    for (int m = 0; m < 4; ++m) {
        int p = p0 + 16 * m + c;
        float y = xyz[3 * p + 1];
        float z = xyz[3 * p + 2];
        float sy1 = __builtin_amdgcn_sinf(y);
        float cy1 = __builtin_amdgcn_cosf(y);
        syp[m] = 0.f; syc[m] = sy1; c2y[m] = 2.f * cy1;
        float sz1 = __builtin_amdgcn_sinf(z);
        float cz1 = __builtin_amdgcn_cosf(z);
        float wv  = __builtin_amdgcn_fractf((float)(8 * g) * z);
        float sb  = __builtin_amdgcn_sinf(wv) * kmask;   // sin(8g*thz), masked
        float cb  = __builtin_amdgcn_cosf(wv);
        float c2z = 2.f * cz1;
        float szf[8];
        szf[0] = sb;
        szf[1] = fmaf(sb, cz1, cb * sz1 * kmask);
#pragma unroll
        for (int e = 2; e < 8; ++e) szf[e] = fmaf(c2z, szf[e - 1], -szf[e - 2]);
#pragma unroll
        for (int q = 0; q < 4; ++q) sz2[m][q] = pk2(szf[2 * q], szf[2 * q + 1]);
    }

    f32x4 acc[4][2] = {};

    const int bslot = (lane < 48) ? lane : 47;  // g==3: A=0, B value irrelevant
    const f16x8* __restrict__ Bg = wsB;

    // main loop: s = j (j=0 contributes 0, skipped); B frags from global (L1-hit),
    // fully unrolled so the compiler pipelines the 46 loads with vmcnt(N) waits.
#pragma unroll
    for (int s = 1; s < 24; ++s) {
        f16x8 b0 = Bg[(2 * s + 0) * 48 + bslot];
        f16x8 b1 = Bg[(2 * s + 1) * 48 + bslot];
#pragma unroll
        for (int m = 0; m < 4; ++m) {
            f16x2 hy2 = pk2(syc[m], syc[m]);       // 1 instr: cvt + broadcast
            u32x4 aw;
#pragma unroll
            for (int q = 0; q < 4; ++q) {          // 4x v_pk_mul_f16
                f16x2 pr = hy2 * sz2[m][q];
                aw[q] = __builtin_bit_cast(unsigned int, pr);
            }
            f16x8 a = __builtin_bit_cast(f16x8, aw);
            acc[m][0] = __builtin_amdgcn_mfma_f32_16x16x32_f16(a, b0, acc[m][0], 0, 0, 0);
            acc[m][1] = __builtin_amdgcn_mfma_f32_16x16x32_f16(a, b1, acc[m][1], 0, 0, 0);
            float nxt = fmaf(c2y[m], syc[m], -syp[m]);
            syp[m] = syc[m]; syc[m] = nxt;
        }
    }

    // scatter T: word (lr*TSTRIDE + c) = pk(acc[t=0][r], acc[t=1][r])
    // word w of a row holds i=w (lo) and i=16+w (hi; i>=24 slots are zero)
    unsigned int* Tw = Tl + wave * (64 * TSTRIDE);
#pragma unroll
    for (int m = 0; m < 4; ++m)
#pragma unroll
        for (int r = 0; r < 4; ++r) {
            int lr = 16 * m + 4 * g + r;          // D row = (lane>>4)*4 + reg
            fp16v2 pk = __builtin_amdgcn_cvt_pkrtz(acc[m][0][r], acc[m][1][r]);
            Tw[lr * TSTRIDE + c] = __builtin_bit_cast(unsigned int, pk);
        }

    // T region is wave-private: drain our own LDS writes; no block barrier anywhere.
    asm volatile("s_waitcnt lgkmcnt(0)" ::: "memory");

    // epilogue: lane owns row lane (64 rows/wave), fully coalesced store
    {
        int p = p0 + lane;
        float s1  = __builtin_amdgcn_sinf(xv);
        float c1  = __builtin_amdgcn_cosf(xv);
        float w16 = __builtin_amdgcn_fractf(16.f * xv);   // 16x exact in f32
        float s16 = __builtin_amdgcn_sinf(w16);
        float c16 = __builtin_amdgcn_cosf(w16);
        const float c2x = 2.f * c1;
        float sA0 = 0.f,  sA1 = s1;                        // sin(2pi*w*x)
        float sB0 = s16,  sB1 = fmaf(s16, c1, c16 * s1);   // sin(2pi*(16+w)*x)
        float res = 0.f;
        const unsigned int* Tr = Tw + lane * TSTRIDE;
#pragma unroll
        for (int w = 0; w < 16; ++w) {
            f16x2 h = __builtin_bit_cast(f16x2, Tr[w]);
            res = fmaf(sA0, (float)h[0], res);
            res = fmaf(sB0, (float)h[1], res);   // i>=24: T==0
            float nA = fmaf(c2x, sA1, -sA0);
            float nB = fmaf(c2x, sB1, -sB0);
            sA0 = sA1; sA1 = nA;
            sB0 = sB1; sB1 = nB;
        }
        out[p] = res;
    }
}

extern "C" void kernel_launch(void* const* d_in, const int* in_sizes, int n_in,
                              void* d_out, int out_size, void* d_ws, size_t ws_size,
                              hipStream_t stream) {
    const float* xyz    = (const float*)d_in[0];
    const float* coeffs = (const float*)d_in[1];
    float* out = (float*)d_out;
    f16x8* wsB = (f16x8*)d_ws;                 // needs 36864 B

    prep_B<<<9, 256, 0, stream>>>(coeffs, wsB);

    const int n = in_sizes[0] / 3;             // 524288 = 1024 blocks * 8 waves * 64
    const int grid = n / 512;
    fourier_main<<<grid, 512, 0, stream>>>(xyz, wsB, out);
}

// Round 10
// 31.004 us; speedup vs baseline: 7.5439x; 1.0310x over previous
//
#include <hip/hip_runtime.h>

typedef _Float16 f16x2 __attribute__((ext_vector_type(2)));
typedef _Float16 f16x8 __attribute__((ext_vector_type(8)));
typedef __fp16   fp16v2 __attribute__((ext_vector_type(2)));   // cvt_pkrtz return type
typedef float    f32x4  __attribute__((ext_vector_type(4)));
typedef float    f32x16 __attribute__((ext_vector_type(16)));
typedef unsigned int u32x4 __attribute__((ext_vector_type(4)));

#define TROWSTR 28   // T row stride in words: 112 B = 16B-aligned -> b128 epilogue reads

__device__ __forceinline__ f16x2 pk2(float lo, float hi) {
    fp16v2 p = __builtin_amdgcn_cvt_pkrtz(lo, hi);
    return __builtin_bit_cast(f16x2, p);
}
__device__ __forceinline__ unsigned int pkbits(f16x2 a, f16x2 b) {
    f16x2 r = a * b;
    return __builtin_bit_cast(unsigned int, r);
}

// ---- prep: C (f32) -> flattened-K f16 B table ----
// wsB[s*64 + l][e] = f16(C[i][kk]), i = l&31 (0 if i>=24), kk = 16s + 8*(l>>5) + e
// (flat C index: C[i][j][k] = coeffs[i*576 + 24j + k] = coeffs[i*576 + kk])
__global__ __launch_bounds__(256) void prep_B(const float* __restrict__ coeffs,
                                              f16x8* __restrict__ wsB)
{
    int chunk = blockIdx.x * 256 + threadIdx.x;   // 0..2303 = 36 steps * 64 lanes
    int s = chunk >> 6, l = chunk & 63;
    int i = l & 31, h = l >> 5;
    f16x8 v;
    if (i < 24) {
        const float* src = coeffs + i * 576 + 16 * s + 8 * h;
#pragma unroll
        for (int e = 0; e < 8; ++e) v[e] = (_Float16)src[e];
    } else {
#pragma unroll
        for (int e = 0; e < 8; ++e) v[e] = (_Float16)0.f;
    }
    wsB[chunk] = v;
}

// ---- main: persistent-B 32x32x16 GEMM, flattened K = (j,k), no pad, no barriers ----
// Per wave: 64 points (2 M-tiles of 32). B table (35 frags, 140 VGPR) loaded ONCE.
// Lane: point row mr = lane&31, k-half h = lane>>5.
// Step s (1..35): element e -> kk = 16s+8h+e; j = (2s+h)/3, k = 8*((2s+h)%3)+e.
// sz stored h-pre-rotated in 3 banks so the bank index (2s)%3 is compile-time.
// sy via Chebyshev recurrence with compile-time-masked skip-advance.
// Native v_sin/v_cos take REVOLUTIONS: sin(2pi*x) = __builtin_amdgcn_sinf(x).
__global__ __launch_bounds__(256, 2) void fourier_main(
    const float* __restrict__ xyz,
    const f16x8* __restrict__ wsB,
    float* __restrict__ out)
{
    __shared__ __align__(16) float Tl[4 * 64 * TROWSTR];   // 28672 B

    const int tid  = threadIdx.x;
    const int wave = tid >> 6;
    const int lane = tid & 63;
    const int h    = lane >> 5;
    const int mr   = lane & 31;
    const bool hb  = (h != 0);

    const int p0 = (blockIdx.x * 4 + wave) * 64;

    // epilogue x preload
    const float xv = xyz[3 * (p0 + lane)];

    // ---- persistent B: 35 fragments in registers (s=0 is all-j=0, skipped) ----
    f16x8 bt[36];
#pragma unroll
    for (int s = 1; s < 36; ++s) bt[s] = wsB[s * 64 + lane];

    // ---- per-M-tile trig state ----
    float syp[2], syc[2], c2y[2];
    f16x2 szR[2][3][4];   // [mtile][rotated bank t][e-pair]; bank t holds k0=8*((t+h)%3)

#pragma unroll
    for (int mt = 0; mt < 2; ++mt) {
        int p = p0 + mt * 32 + mr;
        float y = xyz[3 * p + 1];
        float z = xyz[3 * p + 2];

        float s1y = __builtin_amdgcn_sinf(y);
        float c1y = __builtin_amdgcn_cosf(y);
        c2y[mt] = 2.f * c1y;
        // state (prev,cur) = (sy_{j-1}, sy_j) at s=1: j = h ? 1 : 0
        syc[mt] = hb ? s1y : 0.f;
        syp[mt] = hb ? 0.f : -s1y;

        float s1 = __builtin_amdgcn_sinf(z);
        float c1 = __builtin_amdgcn_cosf(z);
        float w8 = __builtin_amdgcn_fractf(8.f * z);
        float s8 = __builtin_amdgcn_sinf(w8);
        float c8 = __builtin_amdgcn_cosf(w8);
        float s16 = 2.f * s8 * c8;            // double angle
        float c16 = fmaf(2.f * c8, c8, -1.f);
        float c2z = 2.f * c1;

        // build bank t: seeds (s_k0, c_k0) with k0 = 8*((t+h)%3)
#pragma unroll
        for (int t = 0; t < 3; ++t) {
            float sk, ck;
            if (t == 0) { sk = hb ? s8  : 0.f;  ck = hb ? c8  : 1.f;  }
            if (t == 1) { sk = hb ? s16 : s8;   ck = hb ? c16 : c8;   }
            if (t == 2) { sk = hb ? 0.f : s16;  ck = hb ? 1.f : c16;  }
            float v[8];
            v[0] = sk;
            v[1] = fmaf(sk, c1, ck * s1);
#pragma unroll
            for (int e = 2; e < 8; ++e) v[e] = fmaf(c2z, v[e - 1], -v[e - 2]);
#pragma unroll
            for (int q = 0; q < 4; ++q) szR[mt][t][q] = pk2(v[2 * q], v[2 * q + 1]);
        }
    }

    f32x16 acc0 = {};
    f32x16 acc1 = {};

    // ---- main loop: NO memory ops, pure VALU+MFMA ----
#pragma unroll
    for (int s = 1; s < 36; ++s) {
        const int t = (2 * s) % 3;   // compile-time rotated-bank index
        {
            f16x2 hy2 = pk2(syc[0], syc[0]);
            u32x4 aw;
            aw[0] = pkbits(hy2, szR[0][t][0]);
            aw[1] = pkbits(hy2, szR[0][t][1]);
            aw[2] = pkbits(hy2, szR[0][t][2]);
            aw[3] = pkbits(hy2, szR[0][t][3]);
            f16x8 a = __builtin_bit_cast(f16x8, aw);
            acc0 = __builtin_amdgcn_mfma_f32_32x32x16_f16(a, bt[s], acc0, 0, 0, 0);
        }
        {
            f16x2 hy2 = pk2(syc[1], syc[1]);
            u32x4 aw;
            aw[0] = pkbits(hy2, szR[1][t][0]);
            aw[1] = pkbits(hy2, szR[1][t][1]);
            aw[2] = pkbits(hy2, szR[1][t][2]);
            aw[3] = pkbits(hy2, szR[1][t][3]);
            f16x8 a = __builtin_bit_cast(f16x8, aw);
            acc1 = __builtin_amdgcn_mfma_f32_32x32x16_f16(a, bt[s], acc1, 0, 0, 0);
        }
        // advance sy: delta j = 0 iff (2s+h)%3 == 0
        if (s < 35) {
#pragma unroll
            for (int mt = 0; mt < 2; ++mt) {
                float t1 = fmaf(c2y[mt], syc[mt], -syp[mt]);
                if ((s % 3) == 2) {             // both halves advance
                    syp[mt] = syc[mt]; syc[mt] = t1;
                } else {
                    bool stay = ((s % 3) == 0) ? !hb : hb;
                    float np = stay ? syp[mt] : syc[mt];
                    float nc = stay ? syc[mt] : t1;
                    syp[mt] = np; syc[mt] = nc;
                }
            }
        }
    }

    // ---- scatter T (f32, wave-private): D row=(reg&3)+8*(reg>>2)+4h, col=lane&31 ----
    float* Tw = Tl + wave * (64 * TROWSTR);
    if (mr < 24) {
#pragma unroll
        for (int r = 0; r < 16; ++r) {
            int row = (r & 3) + 8 * (r >> 2) + 4 * h;
            Tw[row * TROWSTR + mr]        = acc0[r];
            Tw[(32 + row) * TROWSTR + mr] = acc1[r];
        }
    }
    // T is wave-private; wave-lockstep writes -> wave-local drain suffices
    asm volatile("s_waitcnt lgkmcnt(0)" ::: "memory");

    // ---- epilogue: lane owns point row `lane`; b128 row reads; skip i=0 (sx_0=0) ----
    {
        int p = p0 + lane;
        float s1  = __builtin_amdgcn_sinf(xv);
        float c1  = __builtin_amdgcn_cosf(xv);
        const float c2x = 2.f * c1;
        const f32x4* T4 = (const f32x4*)(Tw + lane * TROWSTR);
        f32x4 tv0 = T4[0], tv1 = T4[1], tv2 = T4[2];
        f32x4 tv3 = T4[3], tv4 = T4[4], tv5 = T4[5];
        float tv[24];
#pragma unroll
        for (int q = 0; q < 4; ++q) {
            tv[q]      = tv0[q]; tv[4 + q]  = tv1[q]; tv[8 + q]  = tv2[q];
            tv[12 + q] = tv3[q]; tv[16 + q] = tv4[q]; tv[20 + q] = tv5[q];
        }
        float sp = 0.f, sc = s1, res = 0.f;
#pragma unroll
        for (int i = 1; i < 24; ++i) {
            res = fmaf(sc, tv[i], res);
            float nx = fmaf(c2x, sc, -sp);
            sp = sc; sc = nx;
        }
        out[p] = res;
    }
}

extern "C" void kernel_launch(void* const* d_in, const int* in_sizes, int n_in,
                              void* d_out, int out_size, void* d_ws, size_t ws_size,
                              hipStream_t stream) {
    const float* xyz    = (const float*)d_in[0];
    const float* coeffs = (const float*)d_in[1];
    float* out = (float*)d_out;
    f16x8* wsB = (f16x8*)d_ws;                 // needs 36864 B

    prep_B<<<9, 256, 0, stream>>>(coeffs, wsB);

    const int n = in_sizes[0] / 3;             // 524288 = 2048 blocks * 4 waves * 64
    const int grid = n / 256;
    fourier_main<<<grid, 256, 0, stream>>>(xyz, wsB, out);
}